// Round 1
// baseline (3924.617 us; speedup 1.0000x reference)
//
#include <hip/hip_runtime.h>
#include <math.h>

#define DS_ 1024
#define DT_ 2048
#define V_  32000
#define SS_ 96
#define ST_ 128
#define VC  128
#define TK  32

// ---------------- helpers ----------------

__device__ __forceinline__ float block_reduce_sum_256(float v) {
  __shared__ float tmp[4];
  #pragma unroll
  for (int off = 32; off; off >>= 1) v += __shfl_xor(v, off);
  const int wid = threadIdx.x >> 6;
  if ((threadIdx.x & 63) == 0) tmp[wid] = v;
  __syncthreads();
  if (threadIdx.x == 0) v = tmp[0] + tmp[1] + tmp[2] + tmp[3];
  return v;  // valid on thread 0 only
}

__device__ __forceinline__ const float* s_base(int b, const float* s_hq, const float* s_hp) {
  return (b < 8) ? (s_hq + (size_t)b * SS_ * DS_) : (s_hp + (size_t)(b - 8) * SS_ * DS_);
}
__device__ __forceinline__ const float* t_base(int b, const float* t_hq, const float* t_hp) {
  return (b < 8) ? (t_hq + (size_t)b * ST_ * DT_) : (t_hp + (size_t)(b - 8) * ST_ * DT_);
}

// ---------------- K1: scores = s_qry @ s_pos^T / TEMP ----------------

__global__ __launch_bounds__(256) void scores_kernel(const float* __restrict__ sq,
                                                     const float* __restrict__ sp,
                                                     float* __restrict__ scores) {
  const int i = blockIdx.x >> 3, j = blockIdx.x & 7;
  float acc = 0.f;
  for (int k = threadIdx.x; k < DS_; k += 256)
    acc += sq[(size_t)i * DS_ + k] * sp[(size_t)j * DS_ + k];
  acc = block_reduce_sum_256(acc);
  if (threadIdx.x == 0) scores[i * 8 + j] = acc * 50.0f;  // 1/TEMP
}

// ---------------- K2: mse accumulation ----------------
// proj[i][d] = sum_k t[i][k] * W_proj[k][d] + b[d]; accumulate (s - proj)^2

__global__ __launch_bounds__(256) void mse_kernel(const float* __restrict__ s_qry,
                                                  const float* __restrict__ s_pos,
                                                  const float* __restrict__ t_qry,
                                                  const float* __restrict__ t_pos,
                                                  const float* __restrict__ Wp,
                                                  const float* __restrict__ bp,
                                                  float* __restrict__ mse_acc) {
  const int blk = blockIdx.x;          // 64 = 2 * 8 * 4
  const int z = blk >> 5;
  const int i = (blk >> 2) & 7;
  const int d = (blk & 3) * 256 + threadIdx.x;
  const float* t = z ? t_pos : t_qry;
  const float* s = z ? s_pos : s_qry;
  const float* trow = t + (size_t)i * DT_;
  float acc = bp[d];
  for (int k = 0; k < DT_; ++k) acc += trow[k] * Wp[(size_t)k * DS_ + d];
  const float diff = s[(size_t)i * DS_ + d] - acc;
  const float v = block_reduce_sum_256(diff * diff);
  if (threadIdx.x == 0) atomicAdd(mse_acc, v);
}

// ---------------- K3: cost matrices (the heavy kernel) ----------------
// Per block: batch b, V-chunk of VC columns. Compute S(32xVC)=sv@W_s, T(32xVC)=tv@W_t,
// accumulate cost1[b][i][j] += sum_v |T[i][v]-S[j][v]|, cost2 += (..)^2.

#define FMA16(a, bb)                                                              \
  acc[0][0] += a.x * bb.x; acc[0][1] += a.x * bb.y; acc[0][2] += a.x * bb.z; acc[0][3] += a.x * bb.w; \
  acc[1][0] += a.y * bb.x; acc[1][1] += a.y * bb.y; acc[1][2] += a.y * bb.z; acc[1][3] += a.y * bb.w; \
  acc[2][0] += a.z * bb.x; acc[2][1] += a.z * bb.y; acc[2][2] += a.z * bb.z; acc[2][3] += a.z * bb.w; \
  acc[3][0] += a.w * bb.x; acc[3][1] += a.w * bb.y; acc[3][2] += a.w * bb.z; acc[3][3] += a.w * bb.w;

template <int K>
__device__ __forceinline__ void gemm_tile(const float* __restrict__ Arows, int lda,
                                          const float* __restrict__ W, int v0,
                                          float (&A)[TK][36], float (&Bt)[TK][VC + 4],
                                          float (&Out)[32][133], int tid) {
  const int r0 = (tid >> 5) * 4;
  const int c0 = (tid & 31) * 4;
  float acc[4][4];
  #pragma unroll
  for (int m = 0; m < 4; ++m)
    #pragma unroll
    for (int n = 0; n < 4; ++n) acc[m][n] = 0.f;

  for (int kt = 0; kt < K / TK; ++kt) {
    // stage A (32 rows x TK cols, stored transposed A[k][r]); float4 global reads
    {
      const int r = tid >> 3, k4 = (tid & 7) * 4;
      const float4 w = *(const float4*)&Arows[(size_t)r * lda + kt * TK + k4];
      A[k4 + 0][r] = w.x; A[k4 + 1][r] = w.y; A[k4 + 2][r] = w.z; A[k4 + 3][r] = w.w;
    }
    // stage B (TK x VC)
    #pragma unroll
    for (int i = 0; i < 4; ++i) {
      const int e = tid + 256 * i;
      const int k = e >> 5, c4 = (e & 31) * 4;
      *(float4*)&Bt[k][c4] = *(const float4*)&W[(size_t)(kt * TK + k) * V_ + v0 + c4];
    }
    __syncthreads();
    #pragma unroll
    for (int k = 0; k < TK; ++k) {
      const float4 a  = *(const float4*)&A[k][r0];
      const float4 bb = *(const float4*)&Bt[k][c0];
      FMA16(a, bb)
    }
    __syncthreads();
  }
  #pragma unroll
  for (int m = 0; m < 4; ++m)
    #pragma unroll
    for (int n = 0; n < 4; ++n) Out[r0 + m][c0 + n] = acc[m][n];
}

__global__ __launch_bounds__(256) void cost_kernel(const float* __restrict__ s_hq,
                                                   const float* __restrict__ s_hp,
                                                   const float* __restrict__ t_hq,
                                                   const float* __restrict__ t_hp,
                                                   const float* __restrict__ Ws,
                                                   const float* __restrict__ Wt,
                                                   float* __restrict__ cost1,
                                                   float* __restrict__ cost2) {
  const int blk = blockIdx.x;     // vc*16 + b  (b minor -> same-vchunk blocks co-resident)
  const int b = blk & 15;
  const int v0 = (blk >> 4) * VC;
  const float* sv = s_base(b, s_hq, s_hp);                       // rows 0..31, stride DS_
  const float* tv = t_base(b, t_hq, t_hp) + (size_t)32 * DT_;    // rows 32..63, stride DT_

  __shared__ float A[TK][36];
  __shared__ float Bt[TK][VC + 4];
  __shared__ float Sl[32][133];
  __shared__ float Tl[32][133];

  const int tid = threadIdx.x;
  gemm_tile<DS_>(sv, DS_, Ws, v0, A, Bt, Sl, tid);
  gemm_tile<DT_>(tv, DT_, Wt, v0, A, Bt, Tl, tid);
  __syncthreads();

  // cost accumulation: 1024 (i,j) pairs, 4 per thread (same i, 4 consecutive j)
  const int ii = tid >> 3;
  const int jj = (tid & 7) * 4;
  float l1[4] = {0, 0, 0, 0}, l2[4] = {0, 0, 0, 0};
  for (int v = 0; v < VC; ++v) {
    const float tval = Tl[ii][v];
    #pragma unroll
    for (int q = 0; q < 4; ++q) {
      const float d = tval - Sl[jj + q][v];
      l1[q] += fabsf(d);
      l2[q] += d * d;
    }
  }
  #pragma unroll
  for (int q = 0; q < 4; ++q) {
    atomicAdd(&cost1[(size_t)b * 1024 + ii * 32 + jj + q], l1[q]);
    atomicAdd(&cost2[(size_t)b * 1024 + ii * 32 + jj + q], l2[q]);
  }
}

// ---------------- K4: Hungarian (16 blocks x 1 wave), + vsd ----------------

__global__ __launch_bounds__(64) void hungarian_kernel(const float* __restrict__ cost1,
                                                       const float* __restrict__ cost2,
                                                       int* __restrict__ idx,
                                                       float* __restrict__ vsd_acc) {
  const int b = blockIdx.x;
  const int lane = threadIdx.x;        // j = lane (valid 0..32)
  const float* C = cost1 + (size_t)b * 1024;
  const double INF = 1e18;
  __shared__ double u[33];

  double vj = 0.0;
  int p = 0;
  const bool isj = (lane >= 1 && lane <= 32);
  if (lane <= 32) u[lane] = 0.0;
  __syncthreads();

  for (int i = 1; i <= 32; ++i) {
    if (lane == 0) p = i;              // p[0] = i
    double minv = INF;
    int way = 0;
    int used = 0;
    int j0 = 0;
    while (true) {
      if (lane == j0) used = 1;
      const int i0 = __shfl(p, j0);
      const double ui0 = u[i0];
      double val = INF;
      if (isj && !used) {
        const double cur = (double)C[(i0 - 1) * 32 + (lane - 1)] - ui0 - vj;
        if (cur < minv) { minv = cur; way = j0; }
        val = minv;
      }
      // argmin (value, then smallest j) across the wave
      double bv = val;
      int bj = lane;
      #pragma unroll
      for (int off = 32; off; off >>= 1) {
        const double ov = __shfl_xor(bv, off);
        const int oj = __shfl_xor(bj, off);
        if (ov < bv || (ov == bv && oj < bj)) { bv = ov; bj = oj; }
      }
      const double delta = bv;
      const int j1 = bj;
      if (used) {
        if (lane <= 32) u[p] += delta;   // distinct p across used lanes
        vj -= delta;
      } else {
        minv -= delta;
      }
      j0 = j1;
      const int pj0 = __shfl(p, j0);
      if (pj0 == 0) break;
    }
    // augment
    while (j0) {
      const int j1 = __shfl(way, j0);
      const int pv = __shfl(p, j1);
      if (lane == j0) p = pv;
      j0 = j1;
    }
  }
  // col_of_row[p[j]-1] = j-1 ; vsd term = cost2[b][p-1][lane-1]
  double term = 0.0;
  if (isj) {
    idx[b * 32 + (p - 1)] = lane - 1;
    term = (double)cost2[(size_t)b * 1024 + (p - 1) * 32 + (lane - 1)];
  }
  #pragma unroll
  for (int off = 32; off; off >>= 1) term += __shfl_xor(term, off);
  if (lane == 0) atomicAdd(vsd_acc, (float)term);
}

// ---------------- K5: inverse norms ----------------
// invn layout: sv [0,512) | st [512,1536) | tv [1536,2048) | tt [2048,3072)

__global__ __launch_bounds__(256) void norms_kernel(const float* __restrict__ s_hq,
                                                    const float* __restrict__ s_hp,
                                                    const float* __restrict__ t_hq,
                                                    const float* __restrict__ t_hp,
                                                    float* __restrict__ invn) {
  const int blk = blockIdx.x;  // 16*192
  const int b = blk / 192, t = blk % 192;
  const float* bs = s_base(b, s_hq, s_hp);
  const float* bt = t_base(b, t_hq, t_hp);
  const float* row;
  int K;
  float* out;
  if (t < 32)       { row = bs + (size_t)t * DS_;            K = DS_; out = invn + b * 32 + t; }
  else if (t < 96)  { row = bs + (size_t)t * DS_;            K = DS_; out = invn + 512 + b * 64 + (t - 32); }
  else if (t < 128) { row = bt + (size_t)(t - 96 + 32) * DT_; K = DT_; out = invn + 1536 + b * 32 + (t - 96); }
  else              { row = bt + (size_t)(t - 128 + 64) * DT_; K = DT_; out = invn + 2048 + b * 64 + (t - 128); }
  float ss = 0.f;
  for (int k = threadIdx.x; k < K; k += 256) { const float x = row[k]; ss += x * x; }
  ss = block_reduce_sum_256(ss);
  if (threadIdx.x == 0) *out = 1.0f / fmaxf(sqrtf(ss), 1e-8f);
}

// ---------------- K6: vlad (smooth-L1 of cosine diffs) ----------------

__global__ __launch_bounds__(64) void vlad_kernel(const float* __restrict__ s_hq,
                                                  const float* __restrict__ s_hp,
                                                  const float* __restrict__ t_hq,
                                                  const float* __restrict__ t_hp,
                                                  const int* __restrict__ idx,
                                                  const float* __restrict__ invn,
                                                  float* __restrict__ vlad_acc) {
  const int b = blockIdx.y, i = blockIdx.x, j = threadIdx.x;  // j in 0..63
  const float* bs = s_base(b, s_hq, s_hp);
  const float* bt = t_base(b, t_hq, t_hp);
  const int is = idx[b * 32 + i];
  const float* a1 = bs + (size_t)is * DS_;          // sv row idx[b][i]
  const float* b1 = bs + (size_t)(32 + j) * DS_;    // st row j
  const float* a2 = bt + (size_t)(32 + i) * DT_;    // tv row i
  const float* b2 = bt + (size_t)(64 + j) * DT_;    // tt row j
  float ds = 0.f, dt = 0.f;
  for (int k = 0; k < DS_; ++k) ds += a1[k] * b1[k];
  for (int k = 0; k < DT_; ++k) dt += a2[k] * b2[k];
  const float cs = ds * invn[b * 32 + is] * invn[512 + b * 64 + j];
  const float ct = dt * invn[1536 + b * 32 + i] * invn[2048 + b * 64 + j];
  const float d = cs - ct;
  const float ad = fabsf(d);
  float s = (ad < 1.f) ? 0.5f * d * d : ad - 0.5f;
  #pragma unroll
  for (int off = 32; off; off >>= 1) s += __shfl_xor(s, off);
  if (j == 0) atomicAdd(vlad_acc, s);
}

// ---------------- K7: finalize ----------------
// accs: [0]=mse_sum(both halves), [1]=vsd_sum, [2]=vlad_sum

__global__ __launch_bounds__(64) void final_kernel(const float* __restrict__ scores,
                                                   const float* __restrict__ accs,
                                                   float* __restrict__ out) {
  const int lane = threadIdx.x;
  float ci = 0.f;
  if (lane < 8) {
    float m = -1e30f;
    for (int j = 0; j < 8; ++j) m = fmaxf(m, scores[lane * 8 + j]);
    float sum = 0.f;
    for (int j = 0; j < 8; ++j) sum += expf(scores[lane * 8 + j] - m);
    const float lse = m + logf(sum);
    ci = scores[lane * 8 + lane] - lse;
  }
  #pragma unroll
  for (int off = 32; off; off >>= 1) ci += __shfl_xor(ci, off);
  if (lane == 0) {
    const float contrastive = -ci / 8.0f;
    const float mse = accs[0] / 16384.0f;           // 0.5*(S1+S2)/8192
    const float vsd = accs[1] / 1024000.0f;         // / (32*32000)
    const float vlad = accs[2] / 2048.0f;           // / (32*64)
    const float distill = (vsd + vlad) / 8.0f;      // Bn = 8
    out[0] = contrastive + mse + distill;
    out[1] = contrastive;
    out[2] = distill;
  }
}

// ---------------- launch ----------------

extern "C" void kernel_launch(void* const* d_in, const int* in_sizes, int n_in,
                              void* d_out, int out_size, void* d_ws, size_t ws_size,
                              hipStream_t stream) {
  const float* s_qry = (const float*)d_in[0];
  const float* s_pos = (const float*)d_in[1];
  const float* t_qry = (const float*)d_in[2];
  const float* t_pos = (const float*)d_in[3];
  const float* s_hq  = (const float*)d_in[4];
  const float* s_hp  = (const float*)d_in[5];
  const float* t_hq  = (const float*)d_in[6];
  const float* t_hp  = (const float*)d_in[7];
  const float* Ws    = (const float*)d_in[8];
  const float* Wt    = (const float*)d_in[9];
  const float* Wp    = (const float*)d_in[10];
  const float* bp    = (const float*)d_in[11];

  float* ws     = (float*)d_ws;
  float* scores = ws;               // 64
  float* cost1  = ws + 64;          // 16384
  float* cost2  = ws + 16448;       // 16384
  float* invn   = ws + 32832;       // 3072
  float* accs   = ws + 35904;       // 3
  int*   idx    = (int*)(ws + 35908); // 512 ints
  const size_t used_bytes = (size_t)(35908 + 512) * 4;

  hipMemsetAsync(d_ws, 0, used_bytes, stream);

  scores_kernel<<<64, 256, 0, stream>>>(s_qry, s_pos, scores);
  mse_kernel<<<64, 256, 0, stream>>>(s_qry, s_pos, t_qry, t_pos, Wp, bp, accs + 0);
  cost_kernel<<<(V_ / VC) * 16, 256, 0, stream>>>(s_hq, s_hp, t_hq, t_hp, Ws, Wt, cost1, cost2);
  norms_kernel<<<16 * 192, 256, 0, stream>>>(s_hq, s_hp, t_hq, t_hp, invn);
  hungarian_kernel<<<16, 64, 0, stream>>>(cost1, cost2, idx, accs + 1);
  vlad_kernel<<<dim3(32, 16), 64, 0, stream>>>(s_hq, s_hp, t_hq, t_hp, idx, invn, accs + 2);
  final_kernel<<<1, 64, 0, stream>>>(scores, accs, (float*)d_out);
}

// Round 2
// 1077.221 us; speedup vs baseline: 3.6433x; 3.6433x over previous
//
#include <hip/hip_runtime.h>
#include <math.h>

#define DS_ 1024
#define DT_ 2048
#define V_  32000
#define SS_ 96
#define ST_ 128

// ---------------- small helpers ----------------

__device__ __forceinline__ float block_reduce_sum_256(float v) {
  __shared__ float tmp[4];
  #pragma unroll
  for (int off = 32; off; off >>= 1) v += __shfl_xor(v, off);
  const int wid = threadIdx.x >> 6;
  if ((threadIdx.x & 63) == 0) tmp[wid] = v;
  __syncthreads();
  if (threadIdx.x == 0) v = tmp[0] + tmp[1] + tmp[2] + tmp[3];
  return v;  // valid on thread 0 only
}

__device__ __forceinline__ const float* s_base(int b, const float* s_hq, const float* s_hp) {
  return (b < 8) ? (s_hq + (size_t)b * SS_ * DS_) : (s_hp + (size_t)(b - 8) * SS_ * DS_);
}
__device__ __forceinline__ const float* t_base(int b, const float* t_hq, const float* t_hp) {
  return (b < 8) ? (t_hq + (size_t)b * ST_ * DT_) : (t_hp + (size_t)(b - 8) * ST_ * DT_);
}

__device__ __forceinline__ unsigned short f2bf(float x) {  // RNE
  unsigned int u = __float_as_uint(x);
  u += 0x7fffu + ((u >> 16) & 1u);
  return (unsigned short)(u >> 16);
}
__device__ __forceinline__ float bf2f(unsigned short u) {
  return __uint_as_float(((unsigned int)u) << 16);
}

using bf16x8 = __attribute__((ext_vector_type(8))) short;
using f32x4  = __attribute__((ext_vector_type(4))) float;
using u16x4  = __attribute__((ext_vector_type(4))) unsigned short;

__device__ __forceinline__ void gll16(const void* g, void* l) {
  __builtin_amdgcn_global_load_lds((const __attribute__((address_space(1))) unsigned int*)g,
                                   (__attribute__((address_space(3))) unsigned int*)l, 16, 0, 0);
}

// ---------------- K1: scores = s_qry @ s_pos^T / TEMP ----------------

__global__ __launch_bounds__(256) void scores_kernel(const float* __restrict__ sq,
                                                     const float* __restrict__ sp,
                                                     float* __restrict__ scores) {
  const int i = blockIdx.x >> 3, j = blockIdx.x & 7;
  float acc = 0.f;
  for (int k = threadIdx.x; k < DS_; k += 256)
    acc += sq[(size_t)i * DS_ + k] * sp[(size_t)j * DS_ + k];
  acc = block_reduce_sum_256(acc);
  if (threadIdx.x == 0) scores[i * 8 + j] = acc * 50.0f;  // 1/TEMP
}

// ---------------- K2a: proj = t @ W_proj (k-split, atomic) ----------------

__global__ __launch_bounds__(256) void proj_kernel(const float* __restrict__ t_qry,
                                                   const float* __restrict__ t_pos,
                                                   const float* __restrict__ Wp,
                                                   float* __restrict__ proj) {
  // 256 blocks = z(2) * i(8) * kc(16); kc chunk = 128 k
  const int blk = blockIdx.x;
  const int z = blk >> 7, i = (blk >> 4) & 7, kc = blk & 15;
  const float* t = (z ? t_pos : t_qry) + (size_t)i * DT_;
  const int d4 = threadIdx.x * 4;
  float4 acc = {0.f, 0.f, 0.f, 0.f};
  for (int k = kc * 128; k < kc * 128 + 128; ++k) {
    const float tv = t[k];
    const float4 w = *(const float4*)&Wp[(size_t)k * DS_ + d4];
    acc.x += tv * w.x; acc.y += tv * w.y; acc.z += tv * w.z; acc.w += tv * w.w;
  }
  float* p = proj + ((size_t)z * 8 + i) * DS_ + d4;
  atomicAdd(&p[0], acc.x); atomicAdd(&p[1], acc.y);
  atomicAdd(&p[2], acc.z); atomicAdd(&p[3], acc.w);
}

// ---------------- K2b: mse sum ----------------

__global__ __launch_bounds__(256) void mse2_kernel(const float* __restrict__ s_qry,
                                                   const float* __restrict__ s_pos,
                                                   const float* __restrict__ proj,
                                                   const float* __restrict__ bp,
                                                   float* __restrict__ mse_acc) {
  const int z = blockIdx.x >> 3, i = blockIdx.x & 7;
  const float* s = (z ? s_pos : s_qry) + (size_t)i * DS_;
  const float* p = proj + ((size_t)z * 8 + i) * DS_;
  float ss = 0.f;
  for (int d = threadIdx.x; d < DS_; d += 256) {
    const float diff = s[d] - (p[d] + bp[d]);
    ss += diff * diff;
  }
  ss = block_reduce_sum_256(ss);
  if (threadIdx.x == 0) atomicAdd(mse_acc, ss);
}

// ---------------- packing / conversion kernels ----------------

__global__ __launch_bounds__(256) void pack_as_kernel(const float* __restrict__ s_hq,
                                                      const float* __restrict__ s_hp,
                                                      unsigned short* __restrict__ As) {
  const int g = blockIdx.x;  // 512
  const int b = g >> 5, i = g & 31;
  const float* src = s_base(b, s_hq, s_hp) + (size_t)i * DS_;
  const int k4 = threadIdx.x * 4;
  const float4 w = *(const float4*)&src[k4];
  u16x4 o; o[0] = f2bf(w.x); o[1] = f2bf(w.y); o[2] = f2bf(w.z); o[3] = f2bf(w.w);
  *(u16x4*)&As[(size_t)g * DS_ + k4] = o;
}

__global__ __launch_bounds__(256) void pack_at_kernel(const float* __restrict__ t_hq,
                                                      const float* __restrict__ t_hp,
                                                      unsigned short* __restrict__ At) {
  const int g = blockIdx.x;  // 512
  const int b = g >> 5, i = g & 31;
  const float* src = t_base(b, t_hq, t_hp) + (size_t)(32 + i) * DT_;
  #pragma unroll
  for (int it = 0; it < 2; ++it) {
    const int k4 = (threadIdx.x + it * 256) * 4;
    const float4 w = *(const float4*)&src[k4];
    u16x4 o; o[0] = f2bf(w.x); o[1] = f2bf(w.y); o[2] = f2bf(w.z); o[3] = f2bf(w.w);
    *(u16x4*)&At[(size_t)g * DT_ + k4] = o;
  }
}

// transpose + fp32->bf16: W[k][v] -> Wbt[v][k]
__global__ __launch_bounds__(256) void convw_kernel(const float* __restrict__ W,
                                                    unsigned short* __restrict__ Wbt,
                                                    int K) {
  __shared__ float tile[64][65];
  const int v0 = blockIdx.x * 64, k0 = blockIdx.y * 64;
  const int tid = threadIdx.x;
  #pragma unroll
  for (int it = 0; it < 4; ++it) {
    const int kr = (tid >> 4) + it * 16;
    const int v4 = (tid & 15) * 4;
    const float4 w = *(const float4*)&W[(size_t)(k0 + kr) * V_ + v0 + v4];
    tile[v4 + 0][kr] = w.x; tile[v4 + 1][kr] = w.y;
    tile[v4 + 2][kr] = w.z; tile[v4 + 3][kr] = w.w;
  }
  __syncthreads();
  #pragma unroll
  for (int it = 0; it < 2; ++it) {
    const int s = tid + it * 256;
    const int v = s >> 3, ch = s & 7;
    const float* src = &tile[v][ch * 8];
    unsigned int o[4];
    #pragma unroll
    for (int q = 0; q < 4; ++q)
      o[q] = (unsigned int)f2bf(src[2 * q]) | ((unsigned int)f2bf(src[2 * q + 1]) << 16);
    uint4 pk = {o[0], o[1], o[2], o[3]};
    *(uint4*)&Wbt[(size_t)(v0 + v) * K + k0 + ch * 8] = pk;
  }
}

// ---------------- K3: MFMA cost kernel ----------------
// block: (v-chunk of 128) x (batch pair). M=64 (2 batches x 32 rows), N=128.
// 4 waves, wave tile 32x64 (mb = wv>>1, nb = wv&1).

__device__ __forceinline__ void stage_pair(const unsigned short* __restrict__ Ab,
                                           const unsigned short* __restrict__ Bb,
                                           int K, int t,
                                           unsigned short* Abuf, unsigned short* Bbuf,
                                           int wv, int lane) {
  // B tile: 128 rows x 32 k (512 slots of 16B); A tile: 64 rows (256 slots)
  {
    int s = wv * 64 + lane;
    int v = s >> 2, c = (s & 3) ^ ((v >> 1) & 3);
    gll16(Bb + (size_t)v * K + t * 32 + c * 8, Bbuf + (size_t)(wv * 64) * 8);
    s += 256; v = s >> 2; c = (s & 3) ^ ((v >> 1) & 3);
    gll16(Bb + (size_t)v * K + t * 32 + c * 8, Bbuf + (size_t)(256 + wv * 64) * 8);
  }
  {
    const int s = wv * 64 + lane;
    const int v = s >> 2, c = (s & 3) ^ ((v >> 1) & 3);
    gll16(Ab + (size_t)v * K + t * 32 + c * 8, Abuf + (size_t)(wv * 64) * 8);
  }
}

__device__ __forceinline__ void compute_step(const unsigned short* Abuf,
                                             const unsigned short* Bbuf,
                                             f32x4 acc[2][4], int mb, int nb, int lane) {
  const int lr = lane & 15, c = lane >> 4;
  bf16x8 af[2], bv[4];
  #pragma unroll
  for (int mf = 0; mf < 2; ++mf) {
    const int row = mb * 32 + mf * 16 + lr;
    af[mf] = *(const bf16x8*)(Abuf + row * 32 + (c ^ ((row >> 1) & 3)) * 8);
  }
  #pragma unroll
  for (int nf = 0; nf < 4; ++nf) {
    const int row = nb * 64 + nf * 16 + lr;
    bv[nf] = *(const bf16x8*)(Bbuf + row * 32 + (c ^ ((row >> 1) & 3)) * 8);
  }
  #pragma unroll
  for (int mf = 0; mf < 2; ++mf)
    #pragma unroll
    for (int nf = 0; nf < 4; ++nf)
      acc[mf][nf] = __builtin_amdgcn_mfma_f32_16x16x32_bf16(af[mf], bv[nf], acc[mf][nf], 0, 0, 0);
}

__device__ __forceinline__ void write_out(f32x4 acc[2][4], unsigned short* Out,
                                          int mb, int nb, int lane, bool rot) {
  const int lr = lane & 15, rq = (lane >> 4) * 4;
  #pragma unroll
  for (int mf = 0; mf < 2; ++mf)
    #pragma unroll
    for (int nf = 0; nf < 4; ++nf)
      #pragma unroll
      for (int q = 0; q < 4; ++q) {
        const int r = mb * 32 + mf * 16 + rq + q;
        const int j = nb * 64 + nf * 16 + lr;
        const int jj = rot ? ((j + ((r & 31) << 2)) & 127) : j;
        Out[r * 128 + jj] = f2bf(acc[mf][nf][q]);
      }
}

__global__ __launch_bounds__(256) void cost_mfma_kernel(const unsigned short* __restrict__ As,
                                                        const unsigned short* __restrict__ At,
                                                        const unsigned short* __restrict__ Wsb,
                                                        const unsigned short* __restrict__ Wtb,
                                                        float* __restrict__ cost1,
                                                        float* __restrict__ cost2) {
  __shared__ __align__(16) unsigned short Bst[2][128 * 32];
  __shared__ __align__(16) unsigned short Ast[2][64 * 32];
  __shared__ __align__(16) unsigned short Slds[64 * 128];
  __shared__ __align__(16) unsigned short Tlds[64 * 128];

  const int bp = blockIdx.x & 7;
  const int v0 = (blockIdx.x >> 3) * 128;
  const int tid = threadIdx.x;
  const int wv = tid >> 6, lane = tid & 63;
  const int mb = wv >> 1, nb = wv & 1;
  const int g0 = bp * 64;

  f32x4 acc[2][4];

  // ---- S GEMM: K=1024, 32 steps ----
  {
    #pragma unroll
    for (int mf = 0; mf < 2; ++mf)
      #pragma unroll
      for (int nf = 0; nf < 4; ++nf) acc[mf][nf] = (f32x4){0.f, 0.f, 0.f, 0.f};
    const unsigned short* Ab = As + (size_t)g0 * DS_;
    const unsigned short* Bb = Wsb + (size_t)v0 * DS_;
    stage_pair(Ab, Bb, DS_, 0, Ast[0], Bst[0], wv, lane);
    __syncthreads();
    for (int t = 0; t < 32; ++t) {
      const int cur = t & 1;
      if (t + 1 < 32) stage_pair(Ab, Bb, DS_, t + 1, Ast[cur ^ 1], Bst[cur ^ 1], wv, lane);
      compute_step(Ast[cur], Bst[cur], acc, mb, nb, lane);
      __syncthreads();
    }
    write_out(acc, Slds, mb, nb, lane, false);
  }

  // ---- T GEMM: K=2048, 64 steps ----
  {
    #pragma unroll
    for (int mf = 0; mf < 2; ++mf)
      #pragma unroll
      for (int nf = 0; nf < 4; ++nf) acc[mf][nf] = (f32x4){0.f, 0.f, 0.f, 0.f};
    const unsigned short* Ab = At + (size_t)g0 * DT_;
    const unsigned short* Bb = Wtb + (size_t)v0 * DT_;
    stage_pair(Ab, Bb, DT_, 0, Ast[0], Bst[0], wv, lane);
    __syncthreads();
    for (int t = 0; t < 64; ++t) {
      const int cur = t & 1;
      if (t + 1 < 64) stage_pair(Ab, Bb, DT_, t + 1, Ast[cur ^ 1], Bst[cur ^ 1], wv, lane);
      compute_step(Ast[cur], Bst[cur], acc, mb, nb, lane);
      __syncthreads();
    }
    write_out(acc, Tlds, mb, nb, lane, true);
  }
  __syncthreads();

  // ---- epilogue: cost1/cost2 over 2 batches x 1024 pairs ----
  const int bb = tid >> 7;
  const int ii = (tid >> 2) & 31;
  const int j8 = (tid & 3) * 8;
  const int trow = bb * 32 + ii;
  float l1[8], l2[8];
  #pragma unroll
  for (int q = 0; q < 8; ++q) { l1[q] = 0.f; l2[q] = 0.f; }
  for (int v = 0; v < 128; v += 4) {
    const int vr = (v + ((trow & 31) << 2)) & 127;
    const u16x4 t4 = *(const u16x4*)&Tlds[trow * 128 + vr];
    float tf[4];
    #pragma unroll
    for (int q = 0; q < 4; ++q) tf[q] = bf2f(t4[q]);
    #pragma unroll
    for (int jj = 0; jj < 8; ++jj) {
      const int srow = bb * 32 + j8 + jj;
      const u16x4 s4 = *(const u16x4*)&Slds[srow * 128 + v];
      #pragma unroll
      for (int q = 0; q < 4; ++q) {
        const float d = tf[q] - bf2f(s4[q]);
        l1[jj] += fabsf(d);
        l2[jj] += d * d;
      }
    }
  }
  const int bglob = bp * 2 + bb;
  #pragma unroll
  for (int jj = 0; jj < 8; ++jj) {
    atomicAdd(&cost1[(size_t)bglob * 1024 + ii * 32 + j8 + jj], l1[jj]);
    atomicAdd(&cost2[(size_t)bglob * 1024 + ii * 32 + j8 + jj], l2[jj]);
  }
}

// ---------------- fallback fp32 cost kernel (round-1, correct) ----------------

#define VC  128
#define TK  32
#define FMA16(a, bb)                                                              \
  facc[0][0] += a.x * bb.x; facc[0][1] += a.x * bb.y; facc[0][2] += a.x * bb.z; facc[0][3] += a.x * bb.w; \
  facc[1][0] += a.y * bb.x; facc[1][1] += a.y * bb.y; facc[1][2] += a.y * bb.z; facc[1][3] += a.y * bb.w; \
  facc[2][0] += a.z * bb.x; facc[2][1] += a.z * bb.y; facc[2][2] += a.z * bb.z; facc[2][3] += a.z * bb.w; \
  facc[3][0] += a.w * bb.x; facc[3][1] += a.w * bb.y; facc[3][2] += a.w * bb.z; facc[3][3] += a.w * bb.w;

template <int K>
__device__ __forceinline__ void gemm_tile(const float* __restrict__ Arows, int lda,
                                          const float* __restrict__ W, int v0,
                                          float (&A)[TK][36], float (&Bt)[TK][VC + 4],
                                          float (&Out)[32][133], int tid) {
  const int r0 = (tid >> 5) * 4;
  const int c0 = (tid & 31) * 4;
  float facc[4][4];
  #pragma unroll
  for (int m = 0; m < 4; ++m)
    #pragma unroll
    for (int n = 0; n < 4; ++n) facc[m][n] = 0.f;
  for (int kt = 0; kt < K / TK; ++kt) {
    {
      const int r = tid >> 3, k4 = (tid & 7) * 4;
      const float4 w = *(const float4*)&Arows[(size_t)r * lda + kt * TK + k4];
      A[k4 + 0][r] = w.x; A[k4 + 1][r] = w.y; A[k4 + 2][r] = w.z; A[k4 + 3][r] = w.w;
    }
    #pragma unroll
    for (int i = 0; i < 4; ++i) {
      const int e = tid + 256 * i;
      const int k = e >> 5, c4 = (e & 31) * 4;
      *(float4*)&Bt[k][c4] = *(const float4*)&W[(size_t)(kt * TK + k) * V_ + v0 + c4];
    }
    __syncthreads();
    #pragma unroll
    for (int k = 0; k < TK; ++k) {
      const float4 a  = *(const float4*)&A[k][r0];
      const float4 bb = *(const float4*)&Bt[k][c0];
      FMA16(a, bb)
    }
    __syncthreads();
  }
  #pragma unroll
  for (int m = 0; m < 4; ++m)
    #pragma unroll
    for (int n = 0; n < 4; ++n) Out[r0 + m][c0 + n] = facc[m][n];
}

__global__ __launch_bounds__(256) void cost_kernel(const float* __restrict__ s_hq,
                                                   const float* __restrict__ s_hp,
                                                   const float* __restrict__ t_hq,
                                                   const float* __restrict__ t_hp,
                                                   const float* __restrict__ Ws,
                                                   const float* __restrict__ Wt,
                                                   float* __restrict__ cost1,
                                                   float* __restrict__ cost2) {
  const int blk = blockIdx.x;
  const int b = blk & 15;
  const int v0 = (blk >> 4) * VC;
  const float* sv = s_base(b, s_hq, s_hp);
  const float* tv = t_base(b, t_hq, t_hp) + (size_t)32 * DT_;
  __shared__ float A[TK][36];
  __shared__ float Bt[TK][VC + 4];
  __shared__ float Sl[32][133];
  __shared__ float Tl[32][133];
  const int tid = threadIdx.x;
  gemm_tile<DS_>(sv, DS_, Ws, v0, A, Bt, Sl, tid);
  gemm_tile<DT_>(tv, DT_, Wt, v0, A, Bt, Tl, tid);
  __syncthreads();
  const int ii = tid >> 3;
  const int jj = (tid & 7) * 4;
  float l1[4] = {0, 0, 0, 0}, l2[4] = {0, 0, 0, 0};
  for (int v = 0; v < VC; ++v) {
    const float tval = Tl[ii][v];
    #pragma unroll
    for (int q = 0; q < 4; ++q) {
      const float d = tval - Sl[jj + q][v];
      l1[q] += fabsf(d);
      l2[q] += d * d;
    }
  }
  #pragma unroll
  for (int q = 0; q < 4; ++q) {
    atomicAdd(&cost1[(size_t)b * 1024 + ii * 32 + jj + q], l1[q]);
    atomicAdd(&cost2[(size_t)b * 1024 + ii * 32 + jj + q], l2[q]);
  }
}

// ---------------- K4: Hungarian (16 blocks x 1 wave), + vsd ----------------

__global__ __launch_bounds__(64) void hungarian_kernel(const float* __restrict__ cost1,
                                                       const float* __restrict__ cost2,
                                                       int* __restrict__ idx,
                                                       float* __restrict__ vsd_acc) {
  const int b = blockIdx.x;
  const int lane = threadIdx.x;
  const float* C = cost1 + (size_t)b * 1024;
  const double INF = 1e18;
  __shared__ double u[33];
  double vj = 0.0;
  int p = 0;
  const bool isj = (lane >= 1 && lane <= 32);
  if (lane <= 32) u[lane] = 0.0;
  __syncthreads();
  for (int i = 1; i <= 32; ++i) {
    if (lane == 0) p = i;
    double minv = INF;
    int way = 0;
    int used = 0;
    int j0 = 0;
    while (true) {
      if (lane == j0) used = 1;
      const int i0 = __shfl(p, j0);
      const double ui0 = u[i0];
      double val = INF;
      if (isj && !used) {
        const double cur = (double)C[(i0 - 1) * 32 + (lane - 1)] - ui0 - vj;
        if (cur < minv) { minv = cur; way = j0; }
        val = minv;
      }
      double bv = val;
      int bj = lane;
      #pragma unroll
      for (int off = 32; off; off >>= 1) {
        const double ov = __shfl_xor(bv, off);
        const int oj = __shfl_xor(bj, off);
        if (ov < bv || (ov == bv && oj < bj)) { bv = ov; bj = oj; }
      }
      const double delta = bv;
      const int j1 = bj;
      if (used) {
        if (lane <= 32) u[p] += delta;
        vj -= delta;
      } else {
        minv -= delta;
      }
      j0 = j1;
      const int pj0 = __shfl(p, j0);
      if (pj0 == 0) break;
    }
    while (j0) {
      const int j1 = __shfl(way, j0);
      const int pv = __shfl(p, j1);
      if (lane == j0) p = pv;
      j0 = j1;
    }
  }
  double term = 0.0;
  if (isj) {
    idx[b * 32 + (p - 1)] = lane - 1;
    term = (double)cost2[(size_t)b * 1024 + (p - 1) * 32 + (lane - 1)];
  }
  #pragma unroll
  for (int off = 32; off; off >>= 1) term += __shfl_xor(term, off);
  if (lane == 0) atomicAdd(vsd_acc, (float)term);
}

// ---------------- K5: inverse norms ----------------

__global__ __launch_bounds__(256) void norms_kernel(const float* __restrict__ s_hq,
                                                    const float* __restrict__ s_hp,
                                                    const float* __restrict__ t_hq,
                                                    const float* __restrict__ t_hp,
                                                    float* __restrict__ invn) {
  const int blk = blockIdx.x;
  const int b = blk / 192, t = blk % 192;
  const float* bs = s_base(b, s_hq, s_hp);
  const float* bt = t_base(b, t_hq, t_hp);
  const float* row;
  int K;
  float* out;
  if (t < 32)       { row = bs + (size_t)t * DS_;             K = DS_; out = invn + b * 32 + t; }
  else if (t < 96)  { row = bs + (size_t)t * DS_;             K = DS_; out = invn + 512 + b * 64 + (t - 32); }
  else if (t < 128) { row = bt + (size_t)(t - 96 + 32) * DT_;  K = DT_; out = invn + 1536 + b * 32 + (t - 96); }
  else              { row = bt + (size_t)(t - 128 + 64) * DT_; K = DT_; out = invn + 2048 + b * 64 + (t - 128); }
  float ss = 0.f;
  for (int k = threadIdx.x; k < K; k += 256) { const float x = row[k]; ss += x * x; }
  ss = block_reduce_sum_256(ss);
  if (threadIdx.x == 0) *out = 1.0f / fmaxf(sqrtf(ss), 1e-8f);
}

// ---------------- K6: vlad (coalesced wave-per-j) ----------------

__global__ __launch_bounds__(256) void vlad_kernel2(const float* __restrict__ s_hq,
                                                    const float* __restrict__ s_hp,
                                                    const float* __restrict__ t_hq,
                                                    const float* __restrict__ t_hp,
                                                    const int* __restrict__ idx,
                                                    const float* __restrict__ invn,
                                                    float* __restrict__ vlad_acc) {
  const int b = blockIdx.x >> 5, i = blockIdx.x & 31;
  const int wv = threadIdx.x >> 6, lane = threadIdx.x & 63;
  const float* bs = s_base(b, s_hq, s_hp);
  const float* bt = t_base(b, t_hq, t_hp);
  const int is = idx[b * 32 + i];
  const float* a1p = bs + (size_t)is * DS_;
  const float* a2p = bt + (size_t)(32 + i) * DT_;
  float a1[16], a2[32];
  #pragma unroll
  for (int q = 0; q < 16; ++q) a1[q] = a1p[lane + 64 * q];
  #pragma unroll
  for (int q = 0; q < 32; ++q) a2[q] = a2p[lane + 64 * q];
  const float in_s = invn[b * 32 + is];
  const float in_t = invn[1536 + b * 32 + i];
  float local = 0.f;
  for (int jj = 0; jj < 16; ++jj) {
    const int j = wv * 16 + jj;
    const float* b1 = bs + (size_t)(32 + j) * DS_;
    const float* b2 = bt + (size_t)(64 + j) * DT_;
    float ds = 0.f, dt = 0.f;
    #pragma unroll
    for (int q = 0; q < 16; ++q) ds += a1[q] * b1[lane + 64 * q];
    #pragma unroll
    for (int q = 0; q < 32; ++q) dt += a2[q] * b2[lane + 64 * q];
    #pragma unroll
    for (int off = 32; off; off >>= 1) {
      ds += __shfl_xor(ds, off);
      dt += __shfl_xor(dt, off);
    }
    if (lane == 0) {
      const float cs = ds * in_s * invn[512 + b * 64 + j];
      const float ct = dt * in_t * invn[2048 + b * 64 + j];
      const float d = cs - ct;
      const float ad = fabsf(d);
      local += (ad < 1.f) ? 0.5f * d * d : ad - 0.5f;
    }
  }
  if (lane == 0) atomicAdd(vlad_acc, local);
}

// ---------------- K7: finalize ----------------

__global__ __launch_bounds__(64) void final_kernel(const float* __restrict__ scores,
                                                   const float* __restrict__ accs,
                                                   float* __restrict__ out) {
  const int lane = threadIdx.x;
  float ci = 0.f;
  if (lane < 8) {
    float m = -1e30f;
    for (int j = 0; j < 8; ++j) m = fmaxf(m, scores[lane * 8 + j]);
    float sum = 0.f;
    for (int j = 0; j < 8; ++j) sum += expf(scores[lane * 8 + j] - m);
    const float lse = m + logf(sum);
    ci = scores[lane * 8 + lane] - lse;
  }
  #pragma unroll
  for (int off = 32; off; off >>= 1) ci += __shfl_xor(ci, off);
  if (lane == 0) {
    const float contrastive = -ci / 8.0f;
    const float mse = accs[0] / 16384.0f;
    const float vsd = accs[1] / 1024000.0f;
    const float vlad = accs[2] / 2048.0f;
    const float distill = (vsd + vlad) / 8.0f;
    out[0] = contrastive + mse + distill;
    out[1] = contrastive;
    out[2] = distill;
  }
}

// ---------------- launch ----------------

extern "C" void kernel_launch(void* const* d_in, const int* in_sizes, int n_in,
                              void* d_out, int out_size, void* d_ws, size_t ws_size,
                              hipStream_t stream) {
  const float* s_qry = (const float*)d_in[0];
  const float* s_pos = (const float*)d_in[1];
  const float* t_qry = (const float*)d_in[2];
  const float* t_pos = (const float*)d_in[3];
  const float* s_hq  = (const float*)d_in[4];
  const float* s_hp  = (const float*)d_in[5];
  const float* t_hq  = (const float*)d_in[6];
  const float* t_hp  = (const float*)d_in[7];
  const float* Ws    = (const float*)d_in[8];
  const float* Wt    = (const float*)d_in[9];
  const float* Wp    = (const float*)d_in[10];
  const float* bp    = (const float*)d_in[11];

  float* ws     = (float*)d_ws;
  float* scores = ws;                   // 64
  float* cost1  = ws + 64;              // 16384
  float* cost2  = ws + 16448;           // 16384
  float* invn   = ws + 32832;           // 3072
  float* accs   = ws + 35904;           // 4
  float* proj   = ws + 35908;           // 16384
  int*   idx    = (int*)(ws + 52292);   // 512 ints
  const size_t small_bytes = (size_t)(52292 + 512) * 4;

  const size_t As_off = 262144;
  const size_t At_off = As_off + 1048576;
  const size_t Ws_off = At_off + 2097152;
  const size_t Wt_off = Ws_off + (size_t)V_ * DS_ * 2;
  const size_t req    = Wt_off + (size_t)V_ * DT_ * 2;

  hipMemsetAsync(d_ws, 0, small_bytes, stream);

  scores_kernel<<<64, 256, 0, stream>>>(s_qry, s_pos, scores);
  proj_kernel<<<256, 256, 0, stream>>>(t_qry, t_pos, Wp, proj);
  mse2_kernel<<<16, 256, 0, stream>>>(s_qry, s_pos, proj, bp, accs + 0);
  norms_kernel<<<16 * 192, 256, 0, stream>>>(s_hq, s_hp, t_hq, t_hp, invn);

  if (ws_size >= req) {
    unsigned short* As  = (unsigned short*)((char*)d_ws + As_off);
    unsigned short* At  = (unsigned short*)((char*)d_ws + At_off);
    unsigned short* Wsb = (unsigned short*)((char*)d_ws + Ws_off);
    unsigned short* Wtb = (unsigned short*)((char*)d_ws + Wt_off);
    pack_as_kernel<<<512, 256, 0, stream>>>(s_hq, s_hp, As);
    pack_at_kernel<<<512, 256, 0, stream>>>(t_hq, t_hp, At);
    convw_kernel<<<dim3(V_ / 64, DS_ / 64), 256, 0, stream>>>(Ws, Wsb, DS_);
    convw_kernel<<<dim3(V_ / 64, DT_ / 64), 256, 0, stream>>>(Wt, Wtb, DT_);
    cost_mfma_kernel<<<(V_ / 128) * 8, 256, 0, stream>>>(As, At, Wsb, Wtb, cost1, cost2);
  } else {
    cost_kernel<<<(V_ / VC) * 16, 256, 0, stream>>>(s_hq, s_hp, t_hq, t_hp, Ws, Wt, cost1, cost2);
  }

  hungarian_kernel<<<16, 64, 0, stream>>>(cost1, cost2, idx, accs + 1);
  vlad_kernel2<<<512, 256, 0, stream>>>(s_hq, s_hp, t_hq, t_hp, idx, invn, accs + 2);
  final_kernel<<<1, 64, 0, stream>>>(scores, accs, (float*)d_out);
}